// Round 1
// baseline (187.000 us; speedup 1.0000x reference)
//
#include <hip/hip_runtime.h>

#define T_ 12
#define N_ 1370
#define C_ 8
#define H_ 64
#define MSEQ 64      // sequences per block
#define LDA 104      // LDS A row stride in bf16 elems (96 cols + 8 pad)

typedef __attribute__((ext_vector_type(8))) short short8;
typedef __attribute__((ext_vector_type(4))) float floatx4;
typedef __attribute__((ext_vector_type(2))) float floatx2;

__device__ __forceinline__ float sigmoid_f(float x) {
  return __builtin_amdgcn_rcpf(1.0f + __builtin_amdgcn_exp2f(x * -1.4426950408889634f));
}
__device__ __forceinline__ float tanh_f(float x) {
  float e = __builtin_amdgcn_exp2f(x * 2.8853900817779268f);
  return 1.0f - 2.0f * __builtin_amdgcn_rcpf(1.0f + e);
}
__device__ __forceinline__ short f2bf(float x) {
  unsigned u = __builtin_bit_cast(unsigned, x);
  u = (u + 0x7fffu + ((u >> 16) & 1u)) >> 16;
  return (short)u;
}
__device__ __forceinline__ short8 load_w8(const float* __restrict__ p) {
  short8 r;
#pragma unroll
  for (int j = 0; j < 8; ++j) r[j] = f2bf(p[j]);
  return r;
}

// One block = 64 sequences. A_lds[buf][row=seq][k]: k 0..63 = h (bf16),
// 64..71 = x_t (bf16), 72..95 = zeros (so B K-chunk2 rows 72..95 are dead).
// Wave w owns hidden units u = w*16 + (lane&15): computes gate cols
// {g*64+u : g in i,f,g,o} for all 64 rows -> i/f/g/o for one (seq,unit)
// land in the same lane reg index -> cell update is per-lane fp32, c never
// leaves registers (full precision); only h is bf16-quantized.
__global__ void __launch_bounds__(256) lstm_kernel(
    const float* __restrict__ x, const float* __restrict__ W_ih,
    const float* __restrict__ W_hh, const float* __restrict__ b_ih,
    const float* __restrict__ b_hh, const float* __restrict__ W_fc,
    const float* __restrict__ b_fc, float* __restrict__ out) {
  __shared__ short A[2][MSEQ][LDA];

  const int tid = threadIdx.x;
  const int wave = tid >> 6;
  const int lane = tid & 63;
  const int m16 = lane & 15;  // A: m row within tile; B: n col
  const int q = lane >> 4;    // quad -> k-group
  const int blk = blockIdx.x;

  // ---- B fragments (weights), loaded once, live in VGPRs across all T ----
  const int u = wave * 16 + m16;  // hidden unit this lane owns
  short8 bf[4][3];
  float bias[4];
#pragma unroll
  for (int g = 0; g < 4; ++g) {
    const int grow = g * 64 + u;            // row of W_hh / W_ih (gate index)
    const float* wr = W_hh + grow * 64;
    bf[g][0] = load_w8(wr + q * 8);         // k = 0..31 chunk
    bf[g][1] = load_w8(wr + 32 + q * 8);    // k = 32..63 chunk
    if (q == 0) {
      bf[g][2] = load_w8(W_ih + grow * 8);  // k = 64..71 (x-projection)
    } else {
      short8 z = {0, 0, 0, 0, 0, 0, 0, 0};  // k = 72..95 dead rows
      bf[g][2] = z;
    }
    bias[g] = b_ih[grow] + b_hh[grow];
  }

  // ---- x staging setup: thread -> (seq row, c-pair) ----
  const int xrow = tid >> 2;
  const int xcp = tid & 3;
  const int s0 = blk * MSEQ + xrow;
  const int bidx = s0 / N_;
  const int nidx = s0 - bidx * N_;
  const float* xptr = x + ((size_t)bidx * T_ * N_ + nidx) * C_ + xcp * 2;

  // ---- prologue: zero both buffers (h0 = 0, pad cols = 0), stage x_0 ----
  {
    int* Ai = (int*)A;
#pragma unroll
    for (int i = tid; i < (2 * MSEQ * LDA) / 2; i += 256) Ai[i] = 0;
  }
  __syncthreads();
  {
    floatx2 v = *(const floatx2*)(xptr);
    unsigned pk = (unsigned short)f2bf(v.x) |
                  ((unsigned)(unsigned short)f2bf(v.y) << 16);
    *(int*)&A[0][xrow][64 + xcp * 2] = pk;
  }
  __syncthreads();

  // ---- recurrence ----
  float cst[4][4];
#pragma unroll
  for (int mt = 0; mt < 4; ++mt)
#pragma unroll
    for (int r = 0; r < 4; ++r) cst[mt][r] = 0.0f;

  for (int t = 0; t < T_; ++t) {
    const int rb = t & 1, wb = rb ^ 1;
    short hreg[16];
#pragma unroll
    for (int mt = 0; mt < 4; ++mt) {
      const short* arow = &A[rb][mt * 16 + m16][0];
      short8 a0 = *(const short8*)(arow + q * 8);
      short8 a1 = *(const short8*)(arow + 32 + q * 8);
      short8 a2 = *(const short8*)(arow + 64 + q * 8);
      floatx4 gi = {bias[0], bias[0], bias[0], bias[0]};
      floatx4 gf = {bias[1], bias[1], bias[1], bias[1]};
      floatx4 gg = {bias[2], bias[2], bias[2], bias[2]};
      floatx4 go = {bias[3], bias[3], bias[3], bias[3]};
      gi = __builtin_amdgcn_mfma_f32_16x16x32_bf16(a0, bf[0][0], gi, 0, 0, 0);
      gf = __builtin_amdgcn_mfma_f32_16x16x32_bf16(a0, bf[1][0], gf, 0, 0, 0);
      gg = __builtin_amdgcn_mfma_f32_16x16x32_bf16(a0, bf[2][0], gg, 0, 0, 0);
      go = __builtin_amdgcn_mfma_f32_16x16x32_bf16(a0, bf[3][0], go, 0, 0, 0);
      gi = __builtin_amdgcn_mfma_f32_16x16x32_bf16(a1, bf[0][1], gi, 0, 0, 0);
      gf = __builtin_amdgcn_mfma_f32_16x16x32_bf16(a1, bf[1][1], gf, 0, 0, 0);
      gg = __builtin_amdgcn_mfma_f32_16x16x32_bf16(a1, bf[2][1], gg, 0, 0, 0);
      go = __builtin_amdgcn_mfma_f32_16x16x32_bf16(a1, bf[3][1], go, 0, 0, 0);
      gi = __builtin_amdgcn_mfma_f32_16x16x32_bf16(a2, bf[0][2], gi, 0, 0, 0);
      gf = __builtin_amdgcn_mfma_f32_16x16x32_bf16(a2, bf[1][2], gf, 0, 0, 0);
      gg = __builtin_amdgcn_mfma_f32_16x16x32_bf16(a2, bf[2][2], gg, 0, 0, 0);
      go = __builtin_amdgcn_mfma_f32_16x16x32_bf16(a2, bf[3][2], go, 0, 0, 0);
#pragma unroll
      for (int r = 0; r < 4; ++r) {
        float iv = sigmoid_f(gi[r]);
        float fv = sigmoid_f(gf[r]);
        float gv = tanh_f(gg[r]);
        float ov = sigmoid_f(go[r]);
        float cc = fv * cst[mt][r] + iv * gv;
        cst[mt][r] = cc;
        hreg[mt * 4 + r] = f2bf(ov * tanh_f(cc));
      }
    }
    // scatter h_{t+1} (bf16) into the other buffer; C/D row = q*4+r
#pragma unroll
    for (int mt = 0; mt < 4; ++mt)
#pragma unroll
      for (int r = 0; r < 4; ++r)
        A[wb][mt * 16 + q * 4 + r][u] = hreg[mt * 4 + r];
    // stage x_{t+1}
    if (t + 1 < T_) {
      floatx2 v = *(const floatx2*)(xptr + (size_t)(t + 1) * (N_ * C_));
      unsigned pk = (unsigned short)f2bf(v.x) |
                    ((unsigned)(unsigned short)f2bf(v.y) << 16);
      *(int*)&A[wb][xrow][64 + xcp * 2] = pk;
    }
    __syncthreads();
  }

  // ---- final FC: y = h_T @ W_fc^T + b_fc  (h_T is in A[0], cols 0..63) ----
  short8 fb0, fb1;
  float fbias = 0.0f;
  if (m16 < 8) {
    const float* wr = W_fc + m16 * 64;
    fb0 = load_w8(wr + q * 8);
    fb1 = load_w8(wr + 32 + q * 8);
    fbias = b_fc[m16];
  } else {
    short8 z = {0, 0, 0, 0, 0, 0, 0, 0};
    fb0 = z;
    fb1 = z;
  }
  {
    const int mt = wave;  // each wave handles one 16-row tile
    const short* arow = &A[0][mt * 16 + m16][0];
    short8 a0 = *(const short8*)(arow + q * 8);
    short8 a1 = *(const short8*)(arow + 32 + q * 8);
    floatx4 acc = {fbias, fbias, fbias, fbias};
    acc = __builtin_amdgcn_mfma_f32_16x16x32_bf16(a0, fb0, acc, 0, 0, 0);
    acc = __builtin_amdgcn_mfma_f32_16x16x32_bf16(a1, fb1, acc, 0, 0, 0);
    if (m16 < 8) {
      const int srow = blk * MSEQ + mt * 16 + q * 4;
#pragma unroll
      for (int r = 0; r < 4; ++r) out[(srow + r) * 8 + m16] = acc[r];
    }
  }
}

extern "C" void kernel_launch(void* const* d_in, const int* in_sizes, int n_in,
                              void* d_out, int out_size, void* d_ws,
                              size_t ws_size, hipStream_t stream) {
  const float* x    = (const float*)d_in[0];
  const float* W_ih = (const float*)d_in[1];
  const float* W_hh = (const float*)d_in[2];
  const float* b_ih = (const float*)d_in[3];
  const float* b_hh = (const float*)d_in[4];
  const float* W_fc = (const float*)d_in[5];
  const float* b_fc = (const float*)d_in[6];
  float* out = (float*)d_out;
  // 87680 sequences / 64 per block = 1370 blocks exactly
  hipLaunchKernelGGL(lstm_kernel, dim3(1370), dim3(256), 0, stream,
                     x, W_ih, W_hh, b_ih, b_hh, W_fc, b_fc, out);
}

// Round 2
// 181.344 us; speedup vs baseline: 1.0312x; 1.0312x over previous
//
#include <hip/hip_runtime.h>

#define T_ 12
#define N_ 1370
#define C_ 8
#define H_ 64
#define MSEQ 32      // sequences per block
#define NT 2         // 16-row tiles per wave
#define LDA 88       // LDS A row stride in shorts (176 B, 16B-aligned, 2-way-max banks)
#define NBLK 2740    // 87680 / 32

typedef __attribute__((ext_vector_type(8))) short short8;
typedef __attribute__((ext_vector_type(4))) float floatx4;

#define NLOG2E -1.4426950408889634f
#define TLOG2E 2.8853901817779268f

__device__ __forceinline__ short f2bf(float x) {
  unsigned u = __builtin_bit_cast(unsigned, x);
  u = (u + 0x7fffu + ((u >> 16) & 1u)) >> 16;
  return (short)u;
}
// HW packed f32->bf16 (gfx950): low16 = bf16(a), high16 = bf16(b)
__device__ __forceinline__ unsigned pk_bf16(float a, float b) {
  unsigned r;
  asm("v_cvt_pk_bf16_f32 %0, %1, %2" : "=v"(r) : "v"(a), "v"(b));
  return r;
}
__device__ __forceinline__ short8 load_w8s(const float* __restrict__ p, float s) {
  short8 r;
#pragma unroll
  for (int j = 0; j < 8; ++j) r[j] = f2bf(p[j] * s);
  return r;
}

// One block = 32 sequences, 4 waves. A[buf][seq][k]: k 0..63 = h (bf16),
// 64..71 = x_t, 72..95 = zeros (dead K rows of chunk 2), 96.. wait LDA=88:
// cols 72..87 zero/pad. Chunk2 covers k 64..95 -> cols 64..87 + 8 virtual?
// NOTE: chunk2 K=32 reads cols 64..95; LDA=88 gives only 64..87. Rows 88..95
// of B are zeroed AND the A read would run past the row. So chunk2 A-read is
// only valid for q<3. Fix: keep LDA large enough: use 104 as before? No:
// q=3 reads cols 88..95 -> next row's cols 0..7 (garbage h values) times
// B rows 88..95 which are ZERO in bf[g][2] -> product is zero regardless.
// B zero rows make any A garbage harmless. (q>=1 lanes hold zero B chunk2.)
// Activation: sigmoid/tanh arg scaling pre-folded into weights+biases:
//   i,f,o rows scaled by -log2e  -> gate = rcp(1+exp2(y))
//   g rows scaled by 2*log2e     -> gate = fma(-2, rcp(1+exp2(y)), 1)
__global__ void __launch_bounds__(256) lstm_kernel(
    const float* __restrict__ x, const float* __restrict__ W_ih,
    const float* __restrict__ W_hh, const float* __restrict__ b_ih,
    const float* __restrict__ b_hh, const float* __restrict__ W_fc,
    const float* __restrict__ b_fc, float* __restrict__ out) {
  __shared__ short A[2][MSEQ][LDA];

  const int tid = threadIdx.x;
  const int wave = tid >> 6;
  const int lane = tid & 63;
  const int m16 = lane & 15;
  const int q = lane >> 4;
  const int blk = blockIdx.x;

  // ---- B fragments (scaled weights), resident in VGPRs across all T ----
  const int u = wave * 16 + m16;  // hidden unit this lane owns
  short8 bf[4][3];
  float bias[4];
#pragma unroll
  for (int g = 0; g < 4; ++g) {
    const float sg = (g == 2) ? TLOG2E : NLOG2E;
    const int grow = g * 64 + u;
    const float* wr = W_hh + grow * 64;
    bf[g][0] = load_w8s(wr + q * 8, sg);
    bf[g][1] = load_w8s(wr + 32 + q * 8, sg);
    if (q == 0) {
      bf[g][2] = load_w8s(W_ih + grow * 8, sg);  // k = 64..71
    } else {
      short8 z = {0, 0, 0, 0, 0, 0, 0, 0};       // k = 72..95 dead
      bf[g][2] = z;
    }
    bias[g] = sg * (b_ih[grow] + b_hh[grow]);
  }

  // ---- x staging: one float per thread: row = tid>>3, col = tid&7 ----
  const int xrow = tid >> 3;
  const int xcol = tid & 7;
  const int s0 = blk * MSEQ + xrow;
  const int bidx = s0 / N_;
  const int nidx = s0 - bidx * N_;
  const float* xptr = x + ((size_t)bidx * T_ * N_ + nidx) * C_ + xcol;

  // ---- zero both buffers (h0=0, dead cols=0), stage x_0 ----
  {
    int* Ai = (int*)A;
#pragma unroll
    for (int i = 0; i < (2 * MSEQ * LDA) / (2 * 256); ++i)
      Ai[i * 256 + tid] = 0;
  }
  __syncthreads();
  A[0][xrow][64 + xcol] = f2bf(*xptr);
  __syncthreads();

  // ---- recurrence ----
  float cst[NT][4];
#pragma unroll
  for (int mt = 0; mt < NT; ++mt)
#pragma unroll
    for (int r = 0; r < 4; ++r) cst[mt][r] = 0.0f;

  for (int t = 0; t < T_; ++t) {
    const int rb = t & 1, wb = rb ^ 1;
#pragma unroll
    for (int mt = 0; mt < NT; ++mt) {
      const short* arow = &A[rb][mt * 16 + m16][0];
      short8 a0 = *(const short8*)(arow + q * 8);
      short8 a1 = *(const short8*)(arow + 32 + q * 8);
      short8 a2 = *(const short8*)(arow + 64 + q * 8);  // q=3 overruns row; B rows zero
      floatx4 gi = {bias[0], bias[0], bias[0], bias[0]};
      floatx4 gf = {bias[1], bias[1], bias[1], bias[1]};
      floatx4 gg = {bias[2], bias[2], bias[2], bias[2]};
      floatx4 go = {bias[3], bias[3], bias[3], bias[3]};
      gi = __builtin_amdgcn_mfma_f32_16x16x32_bf16(a0, bf[0][0], gi, 0, 0, 0);
      gf = __builtin_amdgcn_mfma_f32_16x16x32_bf16(a0, bf[1][0], gf, 0, 0, 0);
      gg = __builtin_amdgcn_mfma_f32_16x16x32_bf16(a0, bf[2][0], gg, 0, 0, 0);
      go = __builtin_amdgcn_mfma_f32_16x16x32_bf16(a0, bf[3][0], go, 0, 0, 0);
      gi = __builtin_amdgcn_mfma_f32_16x16x32_bf16(a1, bf[0][1], gi, 0, 0, 0);
      gf = __builtin_amdgcn_mfma_f32_16x16x32_bf16(a1, bf[1][1], gf, 0, 0, 0);
      gg = __builtin_amdgcn_mfma_f32_16x16x32_bf16(a1, bf[2][1], gg, 0, 0, 0);
      go = __builtin_amdgcn_mfma_f32_16x16x32_bf16(a1, bf[3][1], go, 0, 0, 0);
      gi = __builtin_amdgcn_mfma_f32_16x16x32_bf16(a2, bf[0][2], gi, 0, 0, 0);
      gf = __builtin_amdgcn_mfma_f32_16x16x32_bf16(a2, bf[1][2], gf, 0, 0, 0);
      gg = __builtin_amdgcn_mfma_f32_16x16x32_bf16(a2, bf[2][2], gg, 0, 0, 0);
      go = __builtin_amdgcn_mfma_f32_16x16x32_bf16(a2, bf[3][2], go, 0, 0, 0);
      float hv[4];
#pragma unroll
      for (int r = 0; r < 4; ++r) {
        float iv = __builtin_amdgcn_rcpf(1.0f + __builtin_amdgcn_exp2f(gi[r]));
        float fv = __builtin_amdgcn_rcpf(1.0f + __builtin_amdgcn_exp2f(gf[r]));
        float gv = fmaf(-2.0f, __builtin_amdgcn_rcpf(1.0f + __builtin_amdgcn_exp2f(gg[r])), 1.0f);
        float ov = __builtin_amdgcn_rcpf(1.0f + __builtin_amdgcn_exp2f(go[r]));
        float cc = fmaf(fv, cst[mt][r], iv * gv);
        cst[mt][r] = cc;
        float tc = fmaf(-2.0f, __builtin_amdgcn_rcpf(1.0f + __builtin_amdgcn_exp2f(cc * TLOG2E)), 1.0f);
        hv[r] = ov * tc;
      }
      // scatter h (bf16) into the other buffer; C/D row = q*4+r, col = u
      unsigned p01 = pk_bf16(hv[0], hv[1]);
      unsigned p23 = pk_bf16(hv[2], hv[3]);
      const int rbase = mt * 16 + q * 4;
      A[wb][rbase + 0][u] = (short)p01;
      A[wb][rbase + 1][u] = (short)(p01 >> 16);
      A[wb][rbase + 2][u] = (short)p23;
      A[wb][rbase + 3][u] = (short)(p23 >> 16);
    }
    if (t + 1 < T_) {
      A[wb][xrow][64 + xcol] = f2bf(xptr[(size_t)(t + 1) * (N_ * C_)]);
    }
    __syncthreads();
  }

  // ---- final FC: y = h_T @ W_fc^T + b_fc (h_T in A[0], cols 0..63) ----
  if (wave < NT) {
    short8 fb0, fb1;
    float fbias = 0.0f;
    if (m16 < 8) {
      const float* wr = W_fc + m16 * 64;
      fb0 = load_w8s(wr + q * 8, 1.0f);
      fb1 = load_w8s(wr + 32 + q * 8, 1.0f);
      fbias = b_fc[m16];
    } else {
      short8 z = {0, 0, 0, 0, 0, 0, 0, 0};
      fb0 = z;
      fb1 = z;
    }
    const int mt = wave;
    const short* arow = &A[0][mt * 16 + m16][0];
    short8 a0 = *(const short8*)(arow + q * 8);
    short8 a1 = *(const short8*)(arow + 32 + q * 8);
    floatx4 acc = {fbias, fbias, fbias, fbias};
    acc = __builtin_amdgcn_mfma_f32_16x16x32_bf16(a0, fb0, acc, 0, 0, 0);
    acc = __builtin_amdgcn_mfma_f32_16x16x32_bf16(a1, fb1, acc, 0, 0, 0);
    if (m16 < 8) {
      const int srow = blk * MSEQ + mt * 16 + q * 4;
#pragma unroll
      for (int r = 0; r < 4; ++r) out[(srow + r) * 8 + m16] = acc[r];
    }
  }
}

extern "C" void kernel_launch(void* const* d_in, const int* in_sizes, int n_in,
                              void* d_out, int out_size, void* d_ws,
                              size_t ws_size, hipStream_t stream) {
  const float* x    = (const float*)d_in[0];
  const float* W_ih = (const float*)d_in[1];
  const float* W_hh = (const float*)d_in[2];
  const float* b_ih = (const float*)d_in[3];
  const float* b_hh = (const float*)d_in[4];
  const float* W_fc = (const float*)d_in[5];
  const float* b_fc = (const float*)d_in[6];
  float* out = (float*)d_out;
  hipLaunchKernelGGL(lstm_kernel, dim3(NBLK), dim3(256), 0, stream,
                     x, W_ih, W_hh, b_ih, b_hh, W_fc, b_fc, out);
}

// Round 3
// 169.854 us; speedup vs baseline: 1.1009x; 1.0676x over previous
//
#include <hip/hip_runtime.h>

#define T_ 12
#define N_ 1370
#define MSEQ 32      // sequences per block
#define LDA 72       // h LDS row stride in shorts (144B -> 2-way banks max)
#define LDX 20       // x LDS row stride in shorts (40B -> conflict-free b128)
#define NBLK 2740    // 87680 / 32

typedef __attribute__((ext_vector_type(8))) short short8;
typedef __attribute__((ext_vector_type(4))) float floatx4;

#define NLOG2E -1.4426950408889634f
#define TLOG2E 2.8853900817779268f

__device__ __forceinline__ short f2bf(float x) {
  unsigned u = __builtin_bit_cast(unsigned, x);
  u = (u + 0x7fffu + ((u >> 16) & 1u)) >> 16;
  return (short)u;
}
// HW packed f32->bf16: low16 = bf16(a), high16 = bf16(b)
__device__ __forceinline__ unsigned pk_bf16(float a, float b) {
  unsigned r;
  asm("v_cvt_pk_bf16_f32 %0, %1, %2" : "=v"(r) : "v"(a), "v"(b));
  return r;
}
__device__ __forceinline__ short8 load_w8s(const float* __restrict__ p, float s) {
  short8 r;
#pragma unroll
  for (int j = 0; j < 8; ++j) r[j] = f2bf(p[j] * s);
  return r;
}

// Block = 32 seqs, 4 waves. Swapped MFMA roles: A = weights (m = gate unit),
// B = [h | x | 1] (n = seq). hbuf[buf][seq][unit] bf16; xls[t][seq][0..7]=x,
// [8]=1.0 (bias column), rest 0. A chunk2 per gate: q=0 -> W_ih cols, q=1
// j=0 -> bf16(scaled bias), else 0; B chunk2 q>=1 lanes read the 1.0 column
// (A rows zero there except the bias row, which multiplies the exact 1.0).
// D layout: col=lane&15 = seq, row=q*4+r = unit -> lane owns 4 consecutive
// units of one seq -> i/f/g/o per cell in matching reg r; h writeback is one
// ds_write_b64. Activation scales pre-folded into weights: i,f,o rows by
// -log2e (sigma = 1/(1+2^y)), g rows by 2*log2e (tanh = 1 - 2/(1+2^y)).
// Grouped reciprocal: one v_rcp serves all 4 gate denominators.
__global__ void __launch_bounds__(256, 4) lstm_kernel(
    const float* __restrict__ x, const float* __restrict__ W_ih,
    const float* __restrict__ W_hh, const float* __restrict__ b_ih,
    const float* __restrict__ b_hh, const float* __restrict__ W_fc,
    const float* __restrict__ b_fc, float* __restrict__ out) {
  __shared__ short hbuf[2][MSEQ][LDA];
  __shared__ short xls[T_][MSEQ][LDX];

  const int tid = threadIdx.x;
  const int wave = tid >> 6;
  const int lane = tid & 63;
  const int m16 = lane & 15;
  const int q = lane >> 4;
  const int blk = blockIdx.x;

  // ---- A-operand weight fragments: lane row = unit wave*16+m16 ----
  const int urow = wave * 16 + m16;
  short8 wA[4][3];
#pragma unroll
  for (int g = 0; g < 4; ++g) {
    const float sg = (g == 2) ? TLOG2E : NLOG2E;
    const int grow = g * 64 + urow;
    const float* wr = W_hh + grow * 64;
    wA[g][0] = load_w8s(wr + q * 8, sg);
    wA[g][1] = load_w8s(wr + 32 + q * 8, sg);
    short8 z = {0, 0, 0, 0, 0, 0, 0, 0};
    if (q == 0) {
      wA[g][2] = load_w8s(W_ih + grow * 8, sg);  // k=64..71: x columns
    } else if (q == 1) {
      z[0] = f2bf(sg * (b_ih[grow] + b_hh[grow]));  // k=72: bias column
      wA[g][2] = z;
    } else {
      wA[g][2] = z;  // k=80..95 dead
    }
  }

  // ---- zero LDS (h0 = 0, pads = 0) ----
  {
    int* hp = (int*)hbuf;
#pragma unroll
    for (int i = tid; i < (2 * MSEQ * LDA) / 2; i += 256) hp[i] = 0;
    int* xp = (int*)xls;
#pragma unroll
    for (int i = tid; i < (T_ * MSEQ * LDX) / 2; i += 256) xp[i] = 0;
  }
  __syncthreads();

  // ---- stage all 12 timesteps of x as bf16 + the 1.0 bias column ----
  {
    const int xseq = tid >> 3, xc = tid & 7;
    const int s0 = blk * MSEQ + xseq;
    const int bidx = s0 / N_;
    const int nidx = s0 - bidx * N_;
    const float* xp = x + ((size_t)(bidx * T_) * N_ + nidx) * 8 + xc;
#pragma unroll
    for (int t = 0; t < T_; ++t) {
      xls[t][xseq][xc] = f2bf(xp[(size_t)t * (N_ * 8)]);
      if (xc == 0) xls[t][xseq][8] = (short)0x3F80;  // bf16 1.0
    }
  }
  __syncthreads();

  const int xoff = q ? 8 : 0;  // q>=1 lanes read the 1.0 column region
  const floatx4 zacc = {0.0f, 0.0f, 0.0f, 0.0f};

  float cst[2][4];
#pragma unroll
  for (int nt = 0; nt < 2; ++nt)
#pragma unroll
    for (int r = 0; r < 4; ++r) cst[nt][r] = 0.0f;

  for (int t = 0; t < T_; ++t) {
    const int rb = t & 1, wb = rb ^ 1;
#pragma unroll
    for (int nt = 0; nt < 2; ++nt) {
      const int srow = nt * 16 + m16;
      short8 b0 = *(const short8*)&hbuf[rb][srow][q * 8];
      short8 b1 = *(const short8*)&hbuf[rb][srow][32 + q * 8];
      short8 bx = *(const short8*)&xls[t][srow][xoff];
      floatx4 gi = __builtin_amdgcn_mfma_f32_16x16x32_bf16(wA[0][0], b0, zacc, 0, 0, 0);
      floatx4 gf = __builtin_amdgcn_mfma_f32_16x16x32_bf16(wA[1][0], b0, zacc, 0, 0, 0);
      floatx4 gg = __builtin_amdgcn_mfma_f32_16x16x32_bf16(wA[2][0], b0, zacc, 0, 0, 0);
      floatx4 go = __builtin_amdgcn_mfma_f32_16x16x32_bf16(wA[3][0], b0, zacc, 0, 0, 0);
      gi = __builtin_amdgcn_mfma_f32_16x16x32_bf16(wA[0][1], b1, gi, 0, 0, 0);
      gf = __builtin_amdgcn_mfma_f32_16x16x32_bf16(wA[1][1], b1, gf, 0, 0, 0);
      gg = __builtin_amdgcn_mfma_f32_16x16x32_bf16(wA[2][1], b1, gg, 0, 0, 0);
      go = __builtin_amdgcn_mfma_f32_16x16x32_bf16(wA[3][1], b1, go, 0, 0, 0);
      gi = __builtin_amdgcn_mfma_f32_16x16x32_bf16(wA[0][2], bx, gi, 0, 0, 0);
      gf = __builtin_amdgcn_mfma_f32_16x16x32_bf16(wA[1][2], bx, gf, 0, 0, 0);
      gg = __builtin_amdgcn_mfma_f32_16x16x32_bf16(wA[2][2], bx, gg, 0, 0, 0);
      go = __builtin_amdgcn_mfma_f32_16x16x32_bf16(wA[3][2], bx, go, 0, 0, 0);
      float hv[4];
#pragma unroll
      for (int r = 0; r < 4; ++r) {
        float di = 1.0f + __builtin_amdgcn_exp2f(gi[r]);
        float df = 1.0f + __builtin_amdgcn_exp2f(gf[r]);
        float dg = 1.0f + __builtin_amdgcn_exp2f(gg[r]);
        float dq = 1.0f + __builtin_amdgcn_exp2f(go[r]);
        float pa = di * df, pb = dg * dq;
        float rp = __builtin_amdgcn_rcpf(pa * pb);
        float iv = rp * df * pb;       // 1/di
        float fv = rp * di * pb;       // 1/df
        float gv = fmaf(-2.0f, rp * pa * dq, 1.0f);  // tanh form
        float ov = rp * pa * dg;       // 1/do
        float cc = fmaf(fv, cst[nt][r], iv * gv);
        cst[nt][r] = cc;
        float dt = 1.0f + __builtin_amdgcn_exp2f(cc * TLOG2E);
        float tc = fmaf(-2.0f, __builtin_amdgcn_rcpf(dt), 1.0f);
        hv[r] = ov * tc;
      }
      // one b64 write: h for seq srow, units wave*16+q*4 .. +3
      unsigned long long pk =
          (unsigned long long)pk_bf16(hv[0], hv[1]) |
          ((unsigned long long)pk_bf16(hv[2], hv[3]) << 32);
      *(unsigned long long*)&hbuf[wb][srow][wave * 16 + q * 4] = pk;
    }
    __syncthreads();
  }

  // ---- final FC: y = h_T @ W_fc^T + b_fc; h_T is in hbuf[0] ----
  if (wave < 2) {
    short8 f0, f1;
    short8 z = {0, 0, 0, 0, 0, 0, 0, 0};
    if (m16 < 8) {
      const float* wr = W_fc + m16 * 64;
      f0 = load_w8s(wr + q * 8, 1.0f);
      f1 = load_w8s(wr + 32 + q * 8, 1.0f);
    } else {
      f0 = z;
      f1 = z;
    }
    const int srow = wave * 16 + m16;
    short8 h0 = *(const short8*)&hbuf[0][srow][q * 8];
    short8 h1 = *(const short8*)&hbuf[0][srow][32 + q * 8];
    floatx4 acc = __builtin_amdgcn_mfma_f32_16x16x32_bf16(f0, h0, zacc, 0, 0, 0);
    acc = __builtin_amdgcn_mfma_f32_16x16x32_bf16(f1, h1, acc, 0, 0, 0);
    if (q < 2) {
      const int orow = blk * MSEQ + srow;
#pragma unroll
      for (int r = 0; r < 4; ++r)
        out[orow * 8 + q * 4 + r] = acc[r] + b_fc[q * 4 + r];
    }
  }
}

extern "C" void kernel_launch(void* const* d_in, const int* in_sizes, int n_in,
                              void* d_out, int out_size, void* d_ws,
                              size_t ws_size, hipStream_t stream) {
  const float* x    = (const float*)d_in[0];
  const float* W_ih = (const float*)d_in[1];
  const float* W_hh = (const float*)d_in[2];
  const float* b_ih = (const float*)d_in[3];
  const float* b_hh = (const float*)d_in[4];
  const float* W_fc = (const float*)d_in[5];
  const float* b_fc = (const float*)d_in[6];
  float* out = (float*)d_out;
  hipLaunchKernelGGL(lstm_kernel, dim3(NBLK), dim3(256), 0, stream,
                     x, W_ih, W_hh, b_ih, b_hh, W_fc, b_fc, out);
}